// Round 1
// baseline (744.651 us; speedup 1.0000x reference)
//
#include <hip/hip_runtime.h>
#include <stdint.h>

typedef __attribute__((ext_vector_type(8))) short bf16x8;
typedef __attribute__((ext_vector_type(4))) float f32x4;
typedef __attribute__((ext_vector_type(4))) float fl4;
typedef __attribute__((ext_vector_type(4))) unsigned short u16x4;

constexpr int SEQ = 2048;
constexpr int DMODEL = 1024;
constexpr int NH = 16;
constexpr int DKH = 64;

__device__ __forceinline__ unsigned short f2bf(float x) {
  union { float f; uint32_t u; } c;
  c.f = x;
  uint32_t u = c.u;
  u += 0x7FFFu + ((u >> 16) & 1u);
  return (unsigned short)(u >> 16);
}

__device__ __forceinline__ int swz(int row) { return (row & 3) ^ ((row >> 2) & 3); }

// C[M=8192, N=1024] = A[M,1024] * B[N,1024]^T + bias
// AT: 0 = A is fp32, 1 = A is bf16
// EPI: 0 = store bf16 row-major; 1 = store bf16 transposed per-head V^T [b][h][d][s]; 2 = store fp32 row-major
template <int AT, int EPI>
__global__ __launch_bounds__(256, 2) void gemm_nt(
    const void* __restrict__ Ap, const float* __restrict__ Bw,
    const float* __restrict__ bias, void* __restrict__ Cp) {
  constexpr int K = DMODEL;
  constexpr int N = DMODEL;
  __shared__ unsigned short As[128 * 32];
  __shared__ unsigned short Bs[128 * 32];
  const int tid = threadIdx.x;
  const int wave = tid >> 6, lane = tid & 63;
  const int g = lane >> 4, ln = lane & 15;
  const int r0 = blockIdx.x * 128, c0 = blockIdx.y * 128;
  const int wr = (wave >> 1) * 64, wc = (wave & 1) * 64;
  const int arow = tid >> 2;  // 0..63, +64 on second pass
  const int cc = tid & 3;     // which 8-elem chunk of the 32-wide k slab

  f32x4 acc[4][4] = {};

  for (int kt = 0; kt < K; kt += 32) {
    u16x4 aL[2], aH[2], bL[2], bH[2];
#pragma unroll
    for (int i = 0; i < 2; ++i) {
      const int row = arow + i * 64;
      const long ao = (long)(r0 + row) * K + kt + cc * 8;
      const long bo = (long)(c0 + row) * K + kt + cc * 8;
      if (AT == 0) {
        const float* A = (const float*)Ap;
        fl4 lo = *(const fl4*)(A + ao);
        fl4 hi = *(const fl4*)(A + ao + 4);
#pragma unroll
        for (int j = 0; j < 4; ++j) { aL[i][j] = f2bf(lo[j]); aH[i][j] = f2bf(hi[j]); }
      } else {
        const unsigned short* A = (const unsigned short*)Ap;
        aL[i] = *(const u16x4*)(A + ao);
        aH[i] = *(const u16x4*)(A + ao + 4);
      }
      fl4 blo = *(const fl4*)(Bw + bo);
      fl4 bhi = *(const fl4*)(Bw + bo + 4);
#pragma unroll
      for (int j = 0; j < 4; ++j) { bL[i][j] = f2bf(blo[j]); bH[i][j] = f2bf(bhi[j]); }
    }
    __syncthreads();  // previous iteration's LDS reads done
#pragma unroll
    for (int i = 0; i < 2; ++i) {
      const int row = arow + i * 64;
      const int ch = (cc ^ swz(row)) * 8;
      *(u16x4*)(As + row * 32 + ch) = aL[i];
      *(u16x4*)(As + row * 32 + ch + 4) = aH[i];
      *(u16x4*)(Bs + row * 32 + ch) = bL[i];
      *(u16x4*)(Bs + row * 32 + ch + 4) = bH[i];
    }
    __syncthreads();
    bf16x8 af[4], bfrag[4];
#pragma unroll
    for (int m = 0; m < 4; ++m) {
      const int row = wr + m * 16 + ln;
      af[m] = *(const bf16x8*)(As + row * 32 + ((g ^ swz(row)) * 8));
    }
#pragma unroll
    for (int n = 0; n < 4; ++n) {
      const int row = wc + n * 16 + ln;
      bfrag[n] = *(const bf16x8*)(Bs + row * 32 + ((g ^ swz(row)) * 8));
    }
#pragma unroll
    for (int m = 0; m < 4; ++m)
#pragma unroll
      for (int n = 0; n < 4; ++n)
        acc[m][n] = __builtin_amdgcn_mfma_f32_16x16x32_bf16(af[m], bfrag[n], acc[m][n], 0, 0, 0);
  }

  // epilogue: C/D layout (verified m89): col = lane&15, row = (lane>>4)*4 + reg
#pragma unroll
  for (int m = 0; m < 4; ++m) {
    const int row = r0 + wr + m * 16 + g * 4;
#pragma unroll
    for (int n = 0; n < 4; ++n) {
      const int col = c0 + wc + n * 16 + ln;
      const float bv = bias[col];
      f32x4 v = acc[m][n];
      if (EPI == 2) {
        float* C = (float*)Cp;
#pragma unroll
        for (int r = 0; r < 4; ++r) C[(long)(row + r) * N + col] = v[r] + bv;
      } else if (EPI == 0) {
        unsigned short* C = (unsigned short*)Cp;
#pragma unroll
        for (int r = 0; r < 4; ++r) C[(long)(row + r) * N + col] = f2bf(v[r] + bv);
      } else {
        // V^T: [b][h][d][s], 4 regs = 4 consecutive s
        unsigned short* Vt = (unsigned short*)Cp;
        const int bb = row >> 11, sl = row & 2047;
        const int h = col >> 6, d = col & 63;
        u16x4 pk;
#pragma unroll
        for (int r = 0; r < 4; ++r) pk[r] = f2bf(v[r] + bv);
        *(u16x4*)(Vt + ((long)((bb * NH + h) * DKH + d)) * SEQ + sl) = pk;
      }
    }
  }
}

// Fused: scores (K*Q^T per head) -> softmax over HEADS -> P*V, accumulated over all k.
// Block: 16 q-rows, 4 waves; wave w owns heads [4w, 4w+4). Grid: (S/16, B).
__global__ __launch_bounds__(256, 2) void attn_mid(
    const unsigned short* __restrict__ Qp, const unsigned short* __restrict__ Kp,
    const unsigned short* __restrict__ Vt, unsigned short* __restrict__ Ob) {
  __shared__ float psum[4][32][17];          // [wave][k-local][q] partial exp-sums
  __shared__ unsigned short Pl[NH * 16 * 32]; // per-head P^T patch [h][q16][k32], chunk-swizzled
  const int tid = threadIdx.x;
  const int wave = tid >> 6, lane = tid & 63;
  const int g = lane >> 4, ln = lane & 15;
  const int b = blockIdx.y;
  const int q0 = blockIdx.x * 16;
  const int h0 = wave * 4;

  // Q fragments (B-operand of S^T = K*Q^T): col q = ln, elems = dk
  const long qrow = (long)(b * SEQ + q0 + ln) * DMODEL;
  bf16x8 qf[4][2];
#pragma unroll
  for (int hl = 0; hl < 4; ++hl)
#pragma unroll
    for (int ks = 0; ks < 2; ++ks)
      qf[hl][ks] = *(const bf16x8*)(Qp + qrow + (h0 + hl) * DKH + ks * 32 + g * 8);

  f32x4 ao[4][4] = {};  // [head][d-frag] attn^T accumulators (row=d, col=q)

  for (int k0 = 0; k0 < SEQ; k0 += 32) {
    // S^T[kv,q] = K_tile * Q^T per head
    f32x4 sacc[4][2] = {};
#pragma unroll
    for (int hl = 0; hl < 4; ++hl) {
#pragma unroll
      for (int m = 0; m < 2; ++m) {
        const long krow = (long)(b * SEQ + k0 + m * 16 + ln) * DMODEL + (h0 + hl) * DKH;
#pragma unroll
        for (int ks = 0; ks < 2; ++ks) {
          bf16x8 kf = *(const bf16x8*)(Kp + krow + ks * 32 + g * 8);
          sacc[hl][m] = __builtin_amdgcn_mfma_f32_16x16x32_bf16(kf, qf[hl][ks], sacc[hl][m], 0, 0, 0);
        }
      }
    }
    // exp(s/8) and per-wave (4-head) partial sums; positions: kv = m*16+g*4+r, q = ln
    float e[4][2][4];
    float ps[2][4] = {};
#pragma unroll
    for (int hl = 0; hl < 4; ++hl)
#pragma unroll
      for (int m = 0; m < 2; ++m)
#pragma unroll
        for (int r = 0; r < 4; ++r) {
          float x = __expf(sacc[hl][m][r] * 0.125f);
          e[hl][m][r] = x;
          ps[m][r] += x;
        }
    __syncthreads();  // prior iteration's psum reads complete
#pragma unroll
    for (int m = 0; m < 2; ++m)
#pragma unroll
      for (int r = 0; r < 4; ++r) psum[wave][m * 16 + g * 4 + r][ln] = ps[m][r];
    __syncthreads();  // psums visible
    float rD[2][4];
#pragma unroll
    for (int m = 0; m < 2; ++m)
#pragma unroll
      for (int r = 0; r < 4; ++r) {
        const int kk = m * 16 + g * 4 + r;
        float dsum = psum[0][kk][ln] + psum[1][kk][ln] + psum[2][kk][ln] + psum[3][kk][ln];
        rD[m][r] = __builtin_amdgcn_rcpf(dsum);
      }
    // P^T -> LDS (private per wave; same-wave LDS ordering is in-order, no barrier needed)
#pragma unroll
    for (int hl = 0; hl < 4; ++hl) {
#pragma unroll
      for (int m = 0; m < 2; ++m) {
        u16x4 pk;
#pragma unroll
        for (int r = 0; r < 4; ++r) pk[r] = f2bf(e[hl][m][r] * rD[m][r]);
        // plain ushort pos = kv = m*16 + g*4 + r; chunk = kv/8, swizzled by q
        const int ch = (m * 2 + (g >> 1)) ^ swz(ln);
        *(u16x4*)(Pl + ((h0 + hl) * 16 + ln) * 32 + ch * 8 + (g & 1) * 4) = pk;
      }
    }
    // PV: attn^T[d,q] += V^T (A, from global Vt) * P^T (B, from LDS)
#pragma unroll
    for (int hl = 0; hl < 4; ++hl) {
      bf16x8 pf = *(const bf16x8*)(Pl + ((h0 + hl) * 16 + ln) * 32 + ((g ^ swz(ln)) * 8));
      const long vbase = (long)((b * NH + h0 + hl) * DKH) * SEQ;
#pragma unroll
      for (int m = 0; m < 4; ++m) {
        bf16x8 vf = *(const bf16x8*)(Vt + vbase + (long)(m * 16 + ln) * SEQ + k0 + g * 8);
        ao[hl][m] = __builtin_amdgcn_mfma_f32_16x16x32_bf16(vf, pf, ao[hl][m], 0, 0, 0);
      }
    }
  }

  // epilogue: ao rows = d (m*16+g*4+reg), cols = q (ln); write combined [s][h*64+d] bf16
  const long orow = (long)(b * SEQ + q0 + ln) * DMODEL;
#pragma unroll
  for (int hl = 0; hl < 4; ++hl)
#pragma unroll
    for (int m = 0; m < 4; ++m) {
      u16x4 pk;
#pragma unroll
      for (int r = 0; r < 4; ++r) pk[r] = f2bf(ao[hl][m][r]);
      *(u16x4*)(Ob + orow + (h0 + hl) * DKH + m * 16 + g * 4) = pk;
    }
}

extern "C" void kernel_launch(void* const* d_in, const int* in_sizes, int n_in,
                              void* d_out, int out_size, void* d_ws, size_t ws_size,
                              hipStream_t stream) {
  (void)in_sizes; (void)n_in; (void)out_size; (void)ws_size;
  const float* query = (const float*)d_in[0];
  const float* key   = (const float*)d_in[1];
  const float* value = (const float*)d_in[2];
  const float* Wq = (const float*)d_in[3];
  const float* bq = (const float*)d_in[4];
  const float* Wk = (const float*)d_in[5];
  const float* bk = (const float*)d_in[6];
  const float* Wv = (const float*)d_in[7];
  const float* bv = (const float*)d_in[8];
  const float* Wo = (const float*)d_in[9];
  const float* bo = (const float*)d_in[10];

  uint8_t* ws = (uint8_t*)d_ws;
  const size_t SZ = (size_t)4 * SEQ * DMODEL * 2;  // 16.8 MB per bf16 buffer
  unsigned short* Qp = (unsigned short*)(ws);
  unsigned short* Kp = (unsigned short*)(ws + SZ);
  unsigned short* Vt = (unsigned short*)(ws + 2 * SZ);
  unsigned short* Ab = (unsigned short*)(ws + 3 * SZ);

  dim3 gg(64, 8);
  gemm_nt<0, 0><<<gg, 256, 0, stream>>>(query, Wq, bq, Qp);
  gemm_nt<0, 0><<<gg, 256, 0, stream>>>(key, Wk, bk, Kp);
  gemm_nt<0, 1><<<gg, 256, 0, stream>>>(value, Wv, bv, Vt);
  attn_mid<<<dim3(SEQ / 16, 4), 256, 0, stream>>>(Qp, Kp, Vt, Ab);
  gemm_nt<1, 2><<<gg, 256, 0, stream>>>(Ab, Wo, bo, (float*)d_out);
}

// Round 2
// 610.523 us; speedup vs baseline: 1.2197x; 1.2197x over previous
//
#include <hip/hip_runtime.h>
#include <stdint.h>

typedef __attribute__((ext_vector_type(8))) short bf16x8;
typedef __attribute__((ext_vector_type(4))) float f32x4;
typedef __attribute__((ext_vector_type(4))) float fl4;
typedef __attribute__((ext_vector_type(4))) unsigned short u16x4;

constexpr int SEQ = 2048;
constexpr int DMODEL = 1024;
constexpr int NH = 16;
constexpr int DKH = 64;
constexpr float SEXP = 0.18033688f;  // log2(e)/8 — exp(s/8) == exp2(s*SEXP)

__device__ __forceinline__ unsigned short f2bf(float x) {
  union { float f; uint32_t u; } c;
  c.f = x;
  uint32_t u = c.u;
  u += 0x7FFFu + ((u >> 16) & 1u);
  return (unsigned short)(u >> 16);
}

__device__ __forceinline__ float bf2f(unsigned short u) {
  union { uint32_t u; float f; } c;
  c.u = ((uint32_t)u) << 16;
  return c.f;
}

__device__ __forceinline__ int swz(int row) { return (row & 3) ^ ((row >> 2) & 3); }

__device__ __forceinline__ void gload16(const unsigned short* g, unsigned short* l) {
  __builtin_amdgcn_global_load_lds((const __attribute__((address_space(1))) void*)g,
                                   (__attribute__((address_space(3))) void*)l, 16, 0, 0);
}

// ---------------- projection / output GEMM (unchanged from round 1) ----------------
// C[M=8192, N=1024] = A[M,1024] * B[N,1024]^T + bias
template <int AT, int EPI>
__global__ __launch_bounds__(256, 2) void gemm_nt(
    const void* __restrict__ Ap, const float* __restrict__ Bw,
    const float* __restrict__ bias, void* __restrict__ Cp) {
  constexpr int K = DMODEL;
  constexpr int N = DMODEL;
  __shared__ unsigned short As[128 * 32];
  __shared__ unsigned short Bs[128 * 32];
  const int tid = threadIdx.x;
  const int wave = tid >> 6, lane = tid & 63;
  const int g = lane >> 4, ln = lane & 15;
  const int r0 = blockIdx.x * 128, c0 = blockIdx.y * 128;
  const int wr = (wave >> 1) * 64, wc = (wave & 1) * 64;
  const int arow = tid >> 2;
  const int cc = tid & 3;

  f32x4 acc[4][4] = {};

  for (int kt = 0; kt < K; kt += 32) {
    u16x4 aL[2], aH[2], bL[2], bH[2];
#pragma unroll
    for (int i = 0; i < 2; ++i) {
      const int row = arow + i * 64;
      const long ao = (long)(r0 + row) * K + kt + cc * 8;
      const long bo = (long)(c0 + row) * K + kt + cc * 8;
      if (AT == 0) {
        const float* A = (const float*)Ap;
        fl4 lo = *(const fl4*)(A + ao);
        fl4 hi = *(const fl4*)(A + ao + 4);
#pragma unroll
        for (int j = 0; j < 4; ++j) { aL[i][j] = f2bf(lo[j]); aH[i][j] = f2bf(hi[j]); }
      } else {
        const unsigned short* A = (const unsigned short*)Ap;
        aL[i] = *(const u16x4*)(A + ao);
        aH[i] = *(const u16x4*)(A + ao + 4);
      }
      fl4 blo = *(const fl4*)(Bw + bo);
      fl4 bhi = *(const fl4*)(Bw + bo + 4);
#pragma unroll
      for (int j = 0; j < 4; ++j) { bL[i][j] = f2bf(blo[j]); bH[i][j] = f2bf(bhi[j]); }
    }
    __syncthreads();
#pragma unroll
    for (int i = 0; i < 2; ++i) {
      const int row = arow + i * 64;
      const int ch = (cc ^ swz(row)) * 8;
      *(u16x4*)(As + row * 32 + ch) = aL[i];
      *(u16x4*)(As + row * 32 + ch + 4) = aH[i];
      *(u16x4*)(Bs + row * 32 + ch) = bL[i];
      *(u16x4*)(Bs + row * 32 + ch + 4) = bH[i];
    }
    __syncthreads();
    bf16x8 af[4], bfrag[4];
#pragma unroll
    for (int m = 0; m < 4; ++m) {
      const int row = wr + m * 16 + ln;
      af[m] = *(const bf16x8*)(As + row * 32 + ((g ^ swz(row)) * 8));
    }
#pragma unroll
    for (int n = 0; n < 4; ++n) {
      const int row = wc + n * 16 + ln;
      bfrag[n] = *(const bf16x8*)(Bs + row * 32 + ((g ^ swz(row)) * 8));
    }
#pragma unroll
    for (int m = 0; m < 4; ++m)
#pragma unroll
      for (int n = 0; n < 4; ++n)
        acc[m][n] = __builtin_amdgcn_mfma_f32_16x16x32_bf16(af[m], bfrag[n], acc[m][n], 0, 0, 0);
  }

#pragma unroll
  for (int m = 0; m < 4; ++m) {
    const int row = r0 + wr + m * 16 + g * 4;
#pragma unroll
    for (int n = 0; n < 4; ++n) {
      const int col = c0 + wc + n * 16 + ln;
      const float bv = bias[col];
      f32x4 v = acc[m][n];
      if (EPI == 2) {
        float* C = (float*)Cp;
#pragma unroll
        for (int r = 0; r < 4; ++r) C[(long)(row + r) * N + col] = v[r] + bv;
      } else if (EPI == 0) {
        unsigned short* C = (unsigned short*)Cp;
#pragma unroll
        for (int r = 0; r < 4; ++r) C[(long)(row + r) * N + col] = f2bf(v[r] + bv);
      } else {
        unsigned short* Vt = (unsigned short*)Cp;
        const int bb = row >> 11, sl = row & 2047;
        const int h = col >> 6, d = col & 63;
        u16x4 pk;
#pragma unroll
        for (int r = 0; r < 4; ++r) pk[r] = f2bf(v[r] + bv);
        *(u16x4*)(Vt + ((long)((bb * NH + h) * DKH + d)) * SEQ + sl) = pk;
      }
    }
  }
}

// ---------------- Kernel A: head-softmax denominators ----------------
// Per wave: q64 x kv32, loop over all 16 heads; lane-local sum of exp over heads.
// rD = 1/sum stored bf16 at rDb[b][q][kv]. No LDS, no barriers.
__global__ __launch_bounds__(256, 3) void denomk(
    const unsigned short* __restrict__ Qp, const unsigned short* __restrict__ Kp,
    unsigned short* __restrict__ rDb) {
  const int tid = threadIdx.x, wave = tid >> 6, lane = tid & 63;
  const int g = lane >> 4, ln = lane & 15;
  const int b = blockIdx.z, q0 = blockIdx.y * 64, kv0 = blockIdx.x * 128 + wave * 32;

  f32x4 psum[2][4] = {};

  for (int h = 0; h < NH; ++h) {
    const int hb = h * DKH;
    bf16x8 qf[2][4];
#pragma unroll
    for (int ks = 0; ks < 2; ++ks)
#pragma unroll
      for (int n = 0; n < 4; ++n)
        qf[ks][n] = *(const bf16x8*)(Qp + (size_t)(b * SEQ + q0 + n * 16 + ln) * DMODEL + hb + ks * 32 + g * 8);
    bf16x8 kf[2][2];
#pragma unroll
    for (int m = 0; m < 2; ++m)
#pragma unroll
      for (int ks = 0; ks < 2; ++ks)
        kf[m][ks] = *(const bf16x8*)(Kp + (size_t)(b * SEQ + kv0 + m * 16 + ln) * DMODEL + hb + ks * 32 + g * 8);
    f32x4 s[2][4] = {};
#pragma unroll
    for (int m = 0; m < 2; ++m)
#pragma unroll
      for (int n = 0; n < 4; ++n) {
        s[m][n] = __builtin_amdgcn_mfma_f32_16x16x32_bf16(kf[m][0], qf[0][n], s[m][n], 0, 0, 0);
        s[m][n] = __builtin_amdgcn_mfma_f32_16x16x32_bf16(kf[m][1], qf[1][n], s[m][n], 0, 0, 0);
      }
#pragma unroll
    for (int m = 0; m < 2; ++m)
#pragma unroll
      for (int n = 0; n < 4; ++n)
#pragma unroll
        for (int r = 0; r < 4; ++r) psum[m][n][r] += exp2f(s[m][n][r] * SEXP);
  }

#pragma unroll
  for (int m = 0; m < 2; ++m)
#pragma unroll
    for (int n = 0; n < 4; ++n) {
      u16x4 st;
#pragma unroll
      for (int r = 0; r < 4; ++r) st[r] = f2bf(1.0f / psum[m][n][r]);
      *(u16x4*)(rDb + (size_t)(b * SEQ + q0 + n * 16 + ln) * SEQ + kv0 + m * 16 + g * 4) = st;
    }
}

// ---------------- Kernel B: per-head flash PV with precomputed denominators ----------------
// Block: (b, head-pair hp, q64). Waves: (head = hp*2 + (w>>1), q-half = (w&1)*32).
// K/V staged to LDS via global_load_lds with pre-swizzled source; P transpose via ds_bpermute.
__global__ __launch_bounds__(256, 3) void flashk(
    const unsigned short* __restrict__ Qp, const unsigned short* __restrict__ Kp,
    const unsigned short* __restrict__ Vt, const unsigned short* __restrict__ rDb,
    unsigned short* __restrict__ Ab) {
  __shared__ unsigned short sm[16384];  // K: [64 kv][128 dk] @0, V: [128 d][64 kv] @8192 (both swizzled)
  unsigned short* Ks = sm;
  unsigned short* Vs = sm + 8192;
  const int tid = threadIdx.x, wave = tid >> 6, lane = tid & 63;
  const int g = lane >> 4, ln = lane & 15;
  const int b = blockIdx.z, hp = blockIdx.y, q0 = blockIdx.x * 64;
  const int hl = wave >> 1, h = hp * 2 + hl;
  const int qg = q0 + (wave & 1) * 32;

  bf16x8 qf[2][2];
#pragma unroll
  for (int ks = 0; ks < 2; ++ks)
#pragma unroll
    for (int n = 0; n < 2; ++n)
      qf[ks][n] = *(const bf16x8*)(Qp + (size_t)(b * SEQ + qg + n * 16 + ln) * DMODEL + h * DKH + ks * 32 + g * 8);

  f32x4 ao[4][2] = {};
  const int a0 = ((g & 1) * 32 + ln) * 4;  // bpermute byte index: src lane (g&1)*2, same ln
  const int a1 = a0 + 64;                  // src lane +1
  const bool gl = (g < 2);

  for (int kv0 = 0; kv0 < SEQ; kv0 += 64) {
    // ---- stage K (16KB) ----
#pragma unroll
    for (int i = 0; i < 4; ++i) {
      const int s = i * 256 + tid;
      const int row = s >> 4, c = s & 15;
      const unsigned short* src =
          Kp + (size_t)(b * SEQ + kv0 + row) * DMODEL + hp * 128 + ((c ^ (row & 7)) * 8);
      gload16(src, Ks + (size_t)(i * 256 + wave * 64) * 8);
    }
    // ---- stage V (16KB) ----
#pragma unroll
    for (int i = 0; i < 4; ++i) {
      const int s = i * 256 + tid;
      const int row = s >> 3, c = s & 7;
      const unsigned short* src =
          Vt + ((size_t)((b * NH + hp * 2 + (row >> 6)) * DKH + (row & 63))) * SEQ + kv0 + ((c ^ (row & 7)) * 8);
      gload16(src, Vs + (size_t)(i * 256 + wave * 64) * 8);
    }
    asm volatile("s_waitcnt vmcnt(0)");
    __syncthreads();

#pragma unroll
    for (int si = 0; si < 2; ++si) {
      // QK^T: S^T[kv32, q32] for this head (same MFMA order as denomk)
      f32x4 s2[2][2] = {};
#pragma unroll
      for (int m = 0; m < 2; ++m) {
        const int row = si * 32 + m * 16 + ln;
#pragma unroll
        for (int ks = 0; ks < 2; ++ks) {
          const int c = hl * 8 + ks * 4 + g;
          bf16x8 kf = *(const bf16x8*)(Ks + row * 128 + ((c ^ (row & 7)) * 8));
#pragma unroll
          for (int n = 0; n < 2; ++n)
            s2[m][n] = __builtin_amdgcn_mfma_f32_16x16x32_bf16(kf, qf[ks][n], s2[m][n], 0, 0, 0);
        }
      }
      // P = exp * rD, pack to bf16 pairs, transpose C-layout -> B-frag via bpermute
      bf16x8 pfr[2];
#pragma unroll
      for (int n = 0; n < 2; ++n) {
        uint32_t w[2][2];
#pragma unroll
        for (int m = 0; m < 2; ++m) {
          const size_t ra = (size_t)(b * SEQ + qg + n * 16 + ln) * SEQ + kv0 + si * 32 + m * 16 + g * 4;
          u16x4 rdq = *(const u16x4*)(rDb + ra);
          float p[4];
#pragma unroll
          for (int r = 0; r < 4; ++r) p[r] = exp2f(s2[m][n][r] * SEXP) * bf2f(rdq[r]);
          w[m][0] = (uint32_t)f2bf(p[0]) | ((uint32_t)f2bf(p[1]) << 16);
          w[m][1] = (uint32_t)f2bf(p[2]) | ((uint32_t)f2bf(p[3]) << 16);
        }
        uint32_t pr[4];
#pragma unroll
        for (int j2 = 0; j2 < 4; ++j2) {
          const int ad = (j2 & 2) ? a1 : a0;
          uint32_t b0 = (uint32_t)__builtin_amdgcn_ds_bpermute(ad, (int)w[0][j2 & 1]);
          uint32_t b1 = (uint32_t)__builtin_amdgcn_ds_bpermute(ad, (int)w[1][j2 & 1]);
          pr[j2] = gl ? b0 : b1;
        }
        union { uint32_t u[4]; bf16x8 v; } cvt;
        cvt.u[0] = pr[0]; cvt.u[1] = pr[1]; cvt.u[2] = pr[2]; cvt.u[3] = pr[3];
        pfr[n] = cvt.v;
      }
      // PV: ao^T[d64, q32] += V^T[d, kv32] * P^T[kv32, q32]
#pragma unroll
      for (int dt = 0; dt < 4; ++dt) {
        const int vrow = hl * 64 + dt * 16 + ln;
        const int vc = si * 4 + g;
        bf16x8 vf = *(const bf16x8*)(Vs + vrow * 64 + ((vc ^ (vrow & 7)) * 8));
#pragma unroll
        for (int n = 0; n < 2; ++n)
          ao[dt][n] = __builtin_amdgcn_mfma_f32_16x16x32_bf16(vf, pfr[n], ao[dt][n], 0, 0, 0);
      }
    }
    __syncthreads();
  }

#pragma unroll
  for (int dt = 0; dt < 4; ++dt)
#pragma unroll
    for (int n = 0; n < 2; ++n) {
      u16x4 st;
#pragma unroll
      for (int r = 0; r < 4; ++r) st[r] = f2bf(ao[dt][n][r]);
      *(u16x4*)(Ab + (size_t)(b * SEQ + qg + n * 16 + ln) * DMODEL + h * DKH + dt * 16 + g * 4) = st;
    }
}

extern "C" void kernel_launch(void* const* d_in, const int* in_sizes, int n_in,
                              void* d_out, int out_size, void* d_ws, size_t ws_size,
                              hipStream_t stream) {
  (void)in_sizes; (void)n_in; (void)out_size; (void)ws_size;
  const float* query = (const float*)d_in[0];
  const float* key   = (const float*)d_in[1];
  const float* value = (const float*)d_in[2];
  const float* Wq = (const float*)d_in[3];
  const float* bq = (const float*)d_in[4];
  const float* Wk = (const float*)d_in[5];
  const float* bk = (const float*)d_in[6];
  const float* Wv = (const float*)d_in[7];
  const float* bv = (const float*)d_in[8];
  const float* Wo = (const float*)d_in[9];
  const float* bo = (const float*)d_in[10];

  uint8_t* ws = (uint8_t*)d_ws;
  const size_t SZ = (size_t)4 * SEQ * DMODEL * 2;  // 16.8 MB per bf16 buffer
  unsigned short* Qp = (unsigned short*)(ws);
  unsigned short* Kp = (unsigned short*)(ws + SZ);
  unsigned short* Vt = (unsigned short*)(ws + 2 * SZ);
  unsigned short* Ab = (unsigned short*)(ws + 3 * SZ);
  // rD (bf16, 4*2048*2048*2B = 33.55MB) lives in d_out, which the final GEMM overwrites.
  unsigned short* rDb = (unsigned short*)d_out;

  dim3 gg(64, 8);
  gemm_nt<0, 0><<<gg, 256, 0, stream>>>(query, Wq, bq, Qp);
  gemm_nt<0, 0><<<gg, 256, 0, stream>>>(key, Wk, bk, Kp);
  gemm_nt<0, 1><<<gg, 256, 0, stream>>>(value, Wv, bv, Vt);
  denomk<<<dim3(SEQ / 128, SEQ / 64, 4), 256, 0, stream>>>(Qp, Kp, rDb);
  flashk<<<dim3(SEQ / 64, NH / 2, 4), 256, 0, stream>>>(Qp, Kp, Vt, rDb, Ab);
  gemm_nt<1, 2><<<gg, 256, 0, stream>>>(Ab, Wo, bo, (float*)d_out);
}